// Round 4
// baseline (183.214 us; speedup 1.0000x reference)
//
#include <hip/hip_runtime.h>
#include <math.h>

#if defined(__has_builtin)
#  if __has_builtin(__builtin_amdgcn_exp2f)
#    define EXP2F(x) __builtin_amdgcn_exp2f(x)
#  else
#    define EXP2F(x) exp2f(x)
#  endif
#else
#  define EXP2F(x) exp2f(x)
#endif

constexpr int   DD  = 16;                      // feature dim
constexpr int   SW  = 2;                       // samples per wave (2 => ch[2][16]=32 regs, no AGPR spill)
constexpr float T2  = 72.13475204444817f;      // 50 / ln(2): exp(50*x) = exp2(T2*x)
constexpr float THR = 80.0f;                   // defer-max guard (l<=2^91, fx<=2^96 : overflow-safe)

__device__ __forceinline__ float wave_max64(float v) {
#pragma unroll
    for (int m = 32; m >= 1; m >>= 1) v = fmaxf(v, __shfl_xor(v, m, 64));
    return v;
}
__device__ __forceinline__ float wave_sum64(float v) {
#pragma unroll
    for (int m = 32; m >= 1; m >>= 1) v += __shfl_xor(v, m, 64);
    return v;
}
// force a wave-uniform float into an SGPR
__device__ __forceinline__ float uni(float v) {
    return __int_as_float(__builtin_amdgcn_readfirstlane(__float_as_int(v)));
}

__global__ __launch_bounds__(64, 4)
void finite_fwd(const float* __restrict__ X, const float* __restrict__ Y,
                const float* __restrict__ B, float* __restrict__ out,
                int N, int C)
{
    const int lane  = threadIdx.x & 63;
    const int nbase = blockIdx.x * SW;

    // X rows for this wave's samples — wave-uniform -> SGPRs
    float xs[SW][DD];
#pragma unroll
    for (int i = 0; i < SW; ++i) {
        const float* xp = X + (size_t)(nbase + i) * DD;
#pragma unroll
        for (int k = 0; k < DD; ++k) xs[i][k] = uni(xp[k]);
    }

    // online-softmax state per sample (per-lane partials over this lane's candidates)
    float m2[SW], l[SW], fx[SW], ch[SW][DD];
#pragma unroll
    for (int i = 0; i < SW; ++i) {
        m2[i] = -INFINITY; l[i] = 0.f; fx[i] = 0.f;
#pragma unroll
        for (int k = 0; k < DD; ++k) ch[i][k] = 0.f;
    }

    const int steps = C >> 6;                   // candidates / 64 lanes
    const float4* yq = reinterpret_cast<const float4*>(Y);

    for (int j = 0; j < steps; ++j) {
        const int c = (j << 6) + lane;          // this lane's candidate
        // Y[c][0..15] into registers (coalesced 4KB/wave per step) + bias
        float4 y0 = yq[(size_t)c * 4 + 0];
        float4 y1 = yq[(size_t)c * 4 + 1];
        float4 y2 = yq[(size_t)c * 4 + 2];
        float4 y3 = yq[(size_t)c * 4 + 3];
        float  bv = B[c];
        float yv[DD] = {y0.x,y0.y,y0.z,y0.w, y1.x,y1.y,y1.z,y1.w,
                        y2.x,y2.y,y2.z,y2.w, y3.x,y3.y,y3.z,y3.w};

        float s[SW], arg[SW];
#pragma unroll
        for (int i = 0; i < SW; ++i) {
            float acc = -bv;
#pragma unroll
            for (int k = 0; k < DD; ++k) acc = fmaf(xs[i][k], yv[k], acc);
            s[i]   = acc;                               // score(n_i, c)
            arg[i] = fmaf(acc, T2, -m2[i]);             // exp2 exponent vs lagged max
        }
#pragma unroll
        for (int i = 0; i < SW; ++i) {
            // guarded lagged-max rescale (rare; also fires on first step via m2=-inf -> arg=+inf)
            if (__any(arg[i] > THR)) {
                float smax = wave_max64(s[i]);
                float nm2  = fmaxf(m2[i], smax * T2);
                float sc   = EXP2F(m2[i] - nm2);        // exp2(-inf)=0 handles first step
                l[i]  *= sc;
                fx[i] *= sc;
#pragma unroll
                for (int k = 0; k < DD; ++k) ch[i][k] *= sc;
                m2[i]  = nm2;
                arg[i] = fmaf(s[i], T2, -m2[i]);        // now <= 0 for max lane
            }
            float e = EXP2F(arg[i]);
            l[i] += e;
            fx[i] = fmaf(e, s[i], fx[i]);
#pragma unroll
            for (int k = 0; k < DD; ++k) ch[i][k] = fmaf(e, yv[k], ch[i][k]);
        }
    }

    // cross-lane reductions + normalize + store
#pragma unroll
    for (int i = 0; i < SW; ++i) {
        float lt  = wave_sum64(l[i]);
        float ft  = wave_sum64(fx[i]);
        float inv = 1.0f / lt;
        float cht[DD];
#pragma unroll
        for (int k = 0; k < DD; ++k) cht[k] = wave_sum64(ch[i][k]) * inv;
        if (lane == 0) {
            const int n = nbase + i;
            float4* o = reinterpret_cast<float4*>(out + (size_t)n * DD);
            o[0] = make_float4(cht[0],  cht[1],  cht[2],  cht[3]);
            o[1] = make_float4(cht[4],  cht[5],  cht[6],  cht[7]);
            o[2] = make_float4(cht[8],  cht[9],  cht[10], cht[11]);
            o[3] = make_float4(cht[12], cht[13], cht[14], cht[15]);
            out[(size_t)N * DD + n] = ft * inv;          // f_x
        }
    }
}

extern "C" void kernel_launch(void* const* d_in, const int* in_sizes, int n_in,
                              void* d_out, int out_size, void* d_ws, size_t ws_size,
                              hipStream_t stream) {
    const float* X = (const float*)d_in[0];
    const float* Y = (const float*)d_in[1];   // [1, C, D] contiguous
    const float* B = (const float*)d_in[2];   // [1, C]
    float*     out = (float*)d_out;           // choice [N*D] then f_x [N]

    const int N = in_sizes[0] / DD;           // 32768
    const int C = in_sizes[2];                // 2048 (multiple of 64)

    dim3 grid(N / SW), block(64);
    hipLaunchKernelGGL(finite_fwd, grid, block, 0, stream, X, Y, B, out, N, C);
}

// Round 6
// 102.647 us; speedup vs baseline: 1.7849x; 1.7849x over previous
//
#include <hip/hip_runtime.h>
#include <math.h>

#if defined(__has_builtin)
#  if __has_builtin(__builtin_amdgcn_exp2f)
#    define EXP2F(x) __builtin_amdgcn_exp2f(x)
#  else
#    define EXP2F(x) exp2f(x)
#  endif
#else
#  define EXP2F(x) exp2f(x)
#endif

constexpr int   DD = 16;
constexpr float T2 = 72.13475204444817f;   // 50/ln2
constexpr float DEFER_THR = 8.0f;          // T13 defer-max

typedef __attribute__((ext_vector_type(8)))  short s16x8;
typedef __attribute__((ext_vector_type(16))) float f32x16;

static __device__ __forceinline__ s16x8 mk8(unsigned a, unsigned b, unsigned c, unsigned d) {
    union { unsigned u[4]; s16x8 v; } x;
    x.u[0] = a; x.u[1] = b; x.u[2] = c; x.u[3] = d;
    return x.v;
}
// bf16 truncation packing: element0 (bits[15:0]) = bf16_trunc(a), element1 = bf16_trunc(b)
static __device__ __forceinline__ unsigned pack_tr(float a, float b) {
    return (__float_as_uint(a) >> 16) | (__float_as_uint(b) & 0xFFFF0000u);
}
static __device__ __forceinline__ float trunc_bf(float a) {
    return __uint_as_float(__float_as_uint(a) & 0xFFFF0000u);
}
static __device__ __forceinline__ unsigned short rne16(float f) {
    unsigned u = __float_as_uint(f);
    return (unsigned short)((u + 0x7FFFu + ((u >> 16) & 1u)) >> 16);
}
static __device__ __forceinline__ float bfh2f(unsigned short h) {
    return __uint_as_float(((unsigned)h) << 16);
}

// ---------- prep: split Y into bf16 hi/lo (row-major QK-A) + crow-PERMUTED V^T (PV-A);
// ---------- b into reg-order array bRp and packed QK-bias words Bq ----------
__global__ void prep_kernel(const float* __restrict__ Y, const float* __restrict__ B,
                            unsigned short* __restrict__ YhA, unsigned short* __restrict__ YlA,
                            unsigned short* __restrict__ VhP, unsigned short* __restrict__ VlP,
                            float* __restrict__ bRp, unsigned* __restrict__ Bq, int C)
{
    int c = blockIdx.x * blockDim.x + threadIdx.x;
    if (c >= C) return;

    // slot within 16-block s.t. A-slot (j,hi) holds cand crow(j,hi)=(j&3)+8*(j>>2)+4*hi
    int c15 = c & 15;
    int j    = (c15 & 3) | (((c15 >> 3) & 1) << 2);
    int hslt = (c15 >> 2) & 1;
    int slot = (c & ~15) | (hslt << 3) | j;

    const float* yr = Y + (size_t)c * DD;
#pragma unroll
    for (int d = 0; d < DD; ++d) {
        float y = yr[d];
        unsigned short h = rne16(y);
        unsigned short l = rne16(y - bfh2f(h));
        YhA[(size_t)c * DD + d] = h;
        YlA[(size_t)c * DD + d] = l;
        VhP[(size_t)d * C + slot] = h;
        VlP[(size_t)d * C + slot] = l;
    }
#pragma unroll
    for (int r = DD; r < 32; ++r) {          // zero PV A-rows 16..31
        VhP[(size_t)r * C + slot] = 0;
        VlP[(size_t)r * C + slot] = 0;
    }

    float bb = B[c];
    int t = c >> 5, w5 = c & 31;
    int rr = (w5 & 3) | ((w5 >> 3) << 2);    // reg index r in [0,16)
    int hh = (w5 >> 2) & 1;
    bRp[t * 32 + hh * 16 + rr] = bb;         // b in per-lane reg order

    float qb = -T2 * bb;
    unsigned short qh = rne16(qb);
    unsigned short ql = rne16(qb - bfh2f(qh));
    Bq[c] = (unsigned)qh | ((unsigned)ql << 16);
}

// ---------- main: flash softmax-matmul, 32 samples/block, 4 waves split C ----------
__global__ __launch_bounds__(256, 4)
void finite_mfma(const float* __restrict__ X,
                 const unsigned short* __restrict__ YhA, const unsigned short* __restrict__ YlA,
                 const unsigned short* __restrict__ VhP, const unsigned short* __restrict__ VlP,
                 const float* __restrict__ bRp, const unsigned* __restrict__ Bq,
                 float* __restrict__ out, int N, int C)
{
    const int tid  = threadIdx.x;
    const int wave = tid >> 6, lane = tid & 63;
    const int s = lane & 31, hi = lane >> 5;
    const int n0 = blockIdx.x * 32;
    const int cpw = C >> 2, cbase = wave * cpw, ntile = cpw >> 5;

    __shared__ float bufc[4][16][32];
    __shared__ float lds_l[4][32], lds_fx[4][32], lds_m[4][32];

    // X row for sample n0+s, this half's 8 dims, T2-scaled, trunc-split to bf16 hi/lo
    const float* xp = X + ((size_t)(n0 + s) * DD + 8 * hi);
    float xq[8];
#pragma unroll
    for (int jj = 0; jj < 8; ++jj) xq[jj] = xp[jj] * T2;
    unsigned xhw[4], xlw[4];
#pragma unroll
    for (int jj = 0; jj < 4; ++jj) {
        float a = xq[2 * jj], b = xq[2 * jj + 1];
        xhw[jj] = pack_tr(a, b);
        xlw[jj] = pack_tr(a - trunc_bf(a), b - trunc_bf(b));
    }
    const s16x8 xqh = mk8(xhw[0], xhw[1], xhw[2], xhw[3]);
    const s16x8 xql = mk8(xlw[0], xlw[1], xlw[2], xlw[3]);
    const s16x8 ones2 = mk8(hi ? 0u : 0x3F803F80u, 0u, 0u, 0u);

    f32x16 acc;
#pragma unroll
    for (int r = 0; r < 16; ++r) acc[r] = 0.0f;
    float m2 = -INFINITY, lacc = 0.0f, fxb = 0.0f;

    const size_t vrow = (size_t)s * C;

    for (int t = 0; t < ntile; ++t) {
        const int c0 = cbase + t * 32;
        const s16x8 aYh = *(const s16x8*)(YhA + (size_t)(c0 + s) * DD + 8 * hi);
        const s16x8 aYl = *(const s16x8*)(YlA + (size_t)(c0 + s) * DD + 8 * hi);
        const unsigned bw = Bq[c0 + s];
        const s16x8 a2 = mk8(hi ? 0u : bw, 0u, 0u, 0u);
        const s16x8 vh0 = *(const s16x8*)(VhP + vrow + c0 + 8 * hi);
        const s16x8 vh1 = *(const s16x8*)(VhP + vrow + c0 + 16 + 8 * hi);
        const s16x8 vl0 = *(const s16x8*)(VlP + vrow + c0 + 8 * hi);
        const s16x8 vl1 = *(const s16x8*)(VlP + vrow + c0 + 16 + 8 * hi);
        const float4* brp = (const float4*)(bRp + (size_t)(c0 >> 5) * 32 + hi * 16);
        const float4 br0 = brp[0], br1 = brp[1], br2 = brp[2], br3 = brp[3];

        // S'^T[cand][sample] = T2*(Y.X - b): bias MFMA + 3 split-product MFMAs
        f32x16 S;
#pragma unroll
        for (int r = 0; r < 16; ++r) S[r] = 0.0f;
        S = __builtin_amdgcn_mfma_f32_32x32x16_bf16(a2,  ones2, S, 0, 0, 0);
        S = __builtin_amdgcn_mfma_f32_32x32x16_bf16(aYh, xqh,   S, 0, 0, 0);
        S = __builtin_amdgcn_mfma_f32_32x32x16_bf16(aYh, xql,   S, 0, 0, 0);
        S = __builtin_amdgcn_mfma_f32_32x32x16_bf16(aYl, xqh,   S, 0, 0, 0);

        float tmax = S[0];
#pragma unroll
        for (int r = 1; r < 16; ++r) tmax = fmaxf(tmax, S[r]);
        tmax = fmaxf(tmax, __shfl_xor(tmax, 32, 64));

        if (__any(tmax > m2 + DEFER_THR)) {
            float nm = fmaxf(m2, tmax);
            float sc = EXP2F(m2 - nm);                 // exp2(-inf)=0 on first tile
#pragma unroll
            for (int r = 0; r < 16; ++r) acc[r] *= sc;
            lacc *= sc; fxb *= sc;
            m2 = nm;
        }

        float e[16];
#pragma unroll
        for (int r = 0; r < 16; ++r) e[r] = EXP2F(S[r] - m2);

        const float bR[16] = {br0.x, br0.y, br0.z, br0.w, br1.x, br1.y, br1.z, br1.w,
                              br2.x, br2.y, br2.z, br2.w, br3.x, br3.y, br3.z, br3.w};
#pragma unroll
        for (int r = 0; r < 16; ++r) {
            lacc += e[r];
            fxb = fmaf(e[r], bR[r], fxb);
        }

        // P split to bf16 hi/lo; own regs ARE the B-fragment (V is crow-permuted to match)
        unsigned phw[8], plw[8];
#pragma unroll
        for (int jj = 0; jj < 8; ++jj) {
            float a = e[2 * jj], b = e[2 * jj + 1];
            phw[jj] = pack_tr(a, b);
            plw[jj] = pack_tr(a - trunc_bf(a), b - trunc_bf(b));
        }
        const s16x8 Bph0 = mk8(phw[0], phw[1], phw[2], phw[3]);
        const s16x8 Bpl0 = mk8(plw[0], plw[1], plw[2], plw[3]);
        const s16x8 Bph1 = mk8(phw[4], phw[5], phw[6], phw[7]);
        const s16x8 Bpl1 = mk8(plw[4], plw[5], plw[6], plw[7]);

        acc = __builtin_amdgcn_mfma_f32_32x32x16_bf16(vh0, Bph0, acc, 0, 0, 0);
        acc = __builtin_amdgcn_mfma_f32_32x32x16_bf16(vl0, Bph0, acc, 0, 0, 0);
        acc = __builtin_amdgcn_mfma_f32_32x32x16_bf16(vh0, Bpl0, acc, 0, 0, 0);
        acc = __builtin_amdgcn_mfma_f32_32x32x16_bf16(vh1, Bph1, acc, 0, 0, 0);
        acc = __builtin_amdgcn_mfma_f32_32x32x16_bf16(vl1, Bph1, acc, 0, 0, 0);
        acc = __builtin_amdgcn_mfma_f32_32x32x16_bf16(vh1, Bpl1, acc, 0, 0, 0);
    }

    float l2 = lacc + __shfl_xor(lacc, 32, 64);
    float f2 = fxb  + __shfl_xor(fxb,  32, 64);

    if (hi == 0) lds_m[wave][s] = m2;
    __syncthreads();
    float mstar = fmaxf(fmaxf(lds_m[0][s], lds_m[1][s]), fmaxf(lds_m[2][s], lds_m[3][s]));
    float sw = EXP2F(m2 - mstar);
#pragma unroll
    for (int r = 0; r < 8; ++r) {                      // regs 8..15 are zero-rows: skip
        int dv = (r & 3) + 8 * (r >> 2) + 4 * hi;
        bufc[wave][dv][s] = acc[r] * sw;
    }
    if (hi == 0) { lds_l[wave][s] = l2 * sw; lds_fx[wave][s] = f2 * sw; }
    __syncthreads();

#pragma unroll
    for (int q = 0; q < 2; ++q) {
        int u = tid + 256 * q;
        int dv = u >> 5, ss = u & 31;
        bufc[0][dv][ss] = bufc[0][dv][ss] + bufc[1][dv][ss] + bufc[2][dv][ss] + bufc[3][dv][ss];
    }
    if (tid < 32) {
        lds_l[0][tid]  = lds_l[0][tid]  + lds_l[1][tid]  + lds_l[2][tid]  + lds_l[3][tid];
        lds_fx[0][tid] = lds_fx[0][tid] + lds_fx[1][tid] + lds_fx[2][tid] + lds_fx[3][tid];
    }
    __syncthreads();

    {
        int ss = tid >> 3, d0 = (tid & 7) * 2;
        float inv = 1.0f / lds_l[0][ss];
        float2 o = make_float2(bufc[0][d0][ss] * inv, bufc[0][d0 + 1][ss] * inv);
        *(float2*)(out + (size_t)(n0 + ss) * DD + d0) = o;
    }
    if (tid < 32) {
        float inv = 1.0f / lds_l[0][tid];
        const float* xr = X + (size_t)(n0 + tid) * DD;
        float dot = 0.0f;
#pragma unroll
        for (int d = 0; d < DD; ++d) dot = fmaf(xr[d], bufc[0][d][tid], dot);
        out[(size_t)N * DD + n0 + tid] = (dot - lds_fx[0][tid]) * inv;
    }
}

extern "C" void kernel_launch(void* const* d_in, const int* in_sizes, int n_in,
                              void* d_out, int out_size, void* d_ws, size_t ws_size,
                              hipStream_t stream) {
    const float* X = (const float*)d_in[0];
    const float* Y = (const float*)d_in[1];
    const float* B = (const float*)d_in[2];
    float*     out = (float*)d_out;

    const int N = in_sizes[0] / DD;    // 32768
    const int C = in_sizes[2];         // 2048

    char* w = (char*)d_ws;
    unsigned short* YhA = (unsigned short*)(w);
    unsigned short* YlA = (unsigned short*)(w + (size_t)C * DD * 2);
    unsigned short* VhP = (unsigned short*)(w + (size_t)C * DD * 4);
    unsigned short* VlP = (unsigned short*)(w + (size_t)C * DD * 4 + (size_t)32 * C * 2);
    float*          bRp = (float*)      (w + (size_t)C * DD * 4 + (size_t)32 * C * 4);
    unsigned*       Bq  = (unsigned*)   (w + (size_t)C * DD * 4 + (size_t)32 * C * 4 + (size_t)C * 4);

    hipLaunchKernelGGL(prep_kernel, dim3((C + 255) / 256), dim3(256), 0, stream,
                       Y, B, YhA, YlA, VhP, VlP, bRp, Bq, C);
    hipLaunchKernelGGL(finite_mfma, dim3(N / 32), dim3(256), 0, stream,
                       X, YhA, YlA, VhP, VlP, bRp, Bq, out, N, C);
}

// Round 7
// 95.728 us; speedup vs baseline: 1.9139x; 1.0723x over previous
//
#include <hip/hip_runtime.h>
#include <math.h>

#if defined(__has_builtin)
#  if __has_builtin(__builtin_amdgcn_exp2f)
#    define EXP2F(x) __builtin_amdgcn_exp2f(x)
#  else
#    define EXP2F(x) exp2f(x)
#  endif
#else
#  define EXP2F(x) exp2f(x)
#endif

constexpr int   DD = 16;
constexpr float T2 = 72.13475204444817f;   // 50/ln2
constexpr float DEFER_THR = 8.0f;          // T13 defer-max

typedef __attribute__((ext_vector_type(8)))  short s16x8;
typedef __attribute__((ext_vector_type(16))) float f32x16;

static __device__ __forceinline__ s16x8 mk8(unsigned a, unsigned b, unsigned c, unsigned d) {
    union { unsigned u[4]; s16x8 v; } x;
    x.u[0] = a; x.u[1] = b; x.u[2] = c; x.u[3] = d;
    return x.v;
}
// bf16 truncation packing: element0 (bits[15:0]) = bf16_trunc(a), element1 = bf16_trunc(b)
static __device__ __forceinline__ unsigned pack_tr(float a, float b) {
    return (__float_as_uint(a) >> 16) | (__float_as_uint(b) & 0xFFFF0000u);
}
static __device__ __forceinline__ float trunc_bf(float a) {
    return __uint_as_float(__float_as_uint(a) & 0xFFFF0000u);
}
static __device__ __forceinline__ unsigned short rne16(float f) {
    unsigned u = __float_as_uint(f);
    return (unsigned short)((u + 0x7FFFu + ((u >> 16) & 1u)) >> 16);
}
static __device__ __forceinline__ float bfh2f(unsigned short h) {
    return __uint_as_float(((unsigned)h) << 16);
}

// ---------- prep: Y -> bf16 hi/lo row-major (QK-A) + crow-PERMUTED V^T (PV-A).
// V^T rows 0..15 = dims, row16 = b, row17 = 1.0, rows 18..31 = 0. Bq = packed -T2*b hi/lo ----------
__global__ void prep_kernel(const float* __restrict__ Y, const float* __restrict__ B,
                            unsigned short* __restrict__ YhA, unsigned short* __restrict__ YlA,
                            unsigned short* __restrict__ VhP, unsigned short* __restrict__ VlP,
                            unsigned* __restrict__ Bq, int C)
{
    int c = blockIdx.x * blockDim.x + threadIdx.x;
    if (c >= C) return;

    // slot within 16-block s.t. A-slot (j,hi) holds cand crow(j,hi)=(j&3)+8*(j>>2)+4*hi
    int c15 = c & 15;
    int j    = (c15 & 3) | (((c15 >> 3) & 1) << 2);
    int hslt = (c15 >> 2) & 1;
    int slot = (c & ~15) | (hslt << 3) | j;

    const float* yr = Y + (size_t)c * DD;
#pragma unroll
    for (int d = 0; d < DD; ++d) {
        float y = yr[d];
        unsigned short h = rne16(y);
        unsigned short l = rne16(y - bfh2f(h));
        YhA[(size_t)c * DD + d] = h;
        YlA[(size_t)c * DD + d] = l;
        VhP[(size_t)d * C + slot] = h;
        VlP[(size_t)d * C + slot] = l;
    }
    float bb = B[c];
    unsigned short bh = rne16(bb);
    VhP[(size_t)16 * C + slot] = bh;
    VlP[(size_t)16 * C + slot] = rne16(bb - bfh2f(bh));
    VhP[(size_t)17 * C + slot] = 0x3F80;   // 1.0
    VlP[(size_t)17 * C + slot] = 0;
#pragma unroll
    for (int r = 18; r < 32; ++r) {
        VhP[(size_t)r * C + slot] = 0;
        VlP[(size_t)r * C + slot] = 0;
    }

    float qb = -T2 * bb;
    unsigned short qh = rne16(qb);
    unsigned short ql = rne16(qb - bfh2f(qh));
    Bq[c] = (unsigned)qh | ((unsigned)ql << 16);
}

struct Frag {
    s16x8 aYh, aYl, vh0, vh1, vl0, vl1;
    unsigned bw;
};

// ---------- main: flash softmax-matmul, 32 samples/block, 4 waves split C, reg double-buffer ----------
__global__ __launch_bounds__(256, 4)
void finite_mfma(const float* __restrict__ X,
                 const unsigned short* __restrict__ YhA, const unsigned short* __restrict__ YlA,
                 const unsigned short* __restrict__ VhP, const unsigned short* __restrict__ VlP,
                 const unsigned* __restrict__ Bq,
                 float* __restrict__ out, int N, int C)
{
    const int tid  = threadIdx.x;
    const int wave = tid >> 6, lane = tid & 63;
    const int s = lane & 31, hi = lane >> 5;
    const int n0 = blockIdx.x * 32;
    const int cpw = C >> 2, cbase = wave * cpw, ntile = cpw >> 5;   // 512 cands, 16 tiles

    __shared__ float bufc[4][18][32];
    __shared__ float lds_m[4][32];

    // per-lane streaming pointers (tile stride: Y 512 shorts, V 32 shorts, Bq 32 words)
    const unsigned short* pYh = YhA + ((size_t)(cbase + s) * DD + 8 * hi);
    const unsigned short* pYl = YlA + ((size_t)(cbase + s) * DD + 8 * hi);
    const unsigned short* pVh = VhP + ((size_t)s * C + cbase + 8 * hi);
    const unsigned short* pVl = VlP + ((size_t)s * C + cbase + 8 * hi);
    const unsigned*       pBq = Bq + cbase + s;

    // X row for sample n0+s, this half's 8 dims, T2-scaled, trunc-split to bf16 hi/lo
    const float* xp = X + ((size_t)(n0 + s) * DD + 8 * hi);
    float xq[8];
#pragma unroll
    for (int jj = 0; jj < 8; ++jj) xq[jj] = xp[jj] * T2;
    unsigned xhw[4], xlw[4];
#pragma unroll
    for (int jj = 0; jj < 4; ++jj) {
        float a = xq[2 * jj], b = xq[2 * jj + 1];
        xhw[jj] = pack_tr(a, b);
        xlw[jj] = pack_tr(a - trunc_bf(a), b - trunc_bf(b));
    }
    const s16x8 xqh = mk8(xhw[0], xhw[1], xhw[2], xhw[3]);
    const s16x8 xql = mk8(xlw[0], xlw[1], xlw[2], xlw[3]);
    const s16x8 ones2 = mk8(hi ? 0u : 0x3F803F80u, 0u, 0u, 0u);

    f32x16 acc;
#pragma unroll
    for (int r = 0; r < 16; ++r) acc[r] = 0.0f;
    float m2 = -INFINITY;

#define LDF(F, k) do {                                              \
        (F).aYh = *(const s16x8*)(pYh + (size_t)(k) * 512);         \
        (F).aYl = *(const s16x8*)(pYl + (size_t)(k) * 512);         \
        (F).vh0 = *(const s16x8*)(pVh + (size_t)(k) * 32);          \
        (F).vh1 = *(const s16x8*)(pVh + (size_t)(k) * 32 + 16);     \
        (F).vl0 = *(const s16x8*)(pVl + (size_t)(k) * 32);          \
        (F).vl1 = *(const s16x8*)(pVl + (size_t)(k) * 32 + 16);     \
        (F).bw  = pBq[(size_t)(k) * 32];                            \
    } while (0)

#define PROC(F) do {                                                            \
        const s16x8 a2 = mk8(hi ? 0u : (F).bw, 0u, 0u, 0u);                     \
        f32x16 S;                                                               \
        _Pragma("unroll")                                                       \
        for (int r = 0; r < 16; ++r) S[r] = 0.0f;                               \
        S = __builtin_amdgcn_mfma_f32_32x32x16_bf16(a2,     ones2, S, 0, 0, 0); \
        S = __builtin_amdgcn_mfma_f32_32x32x16_bf16((F).aYh, xqh,  S, 0, 0, 0); \
        S = __builtin_amdgcn_mfma_f32_32x32x16_bf16((F).aYh, xql,  S, 0, 0, 0); \
        S = __builtin_amdgcn_mfma_f32_32x32x16_bf16((F).aYl, xqh,  S, 0, 0, 0); \
        float tmax = S[0];                                                      \
        _Pragma("unroll")                                                       \
        for (int r = 1; r < 16; ++r) tmax = fmaxf(tmax, S[r]);                  \
        tmax = fmaxf(tmax, __shfl_xor(tmax, 32, 64));                           \
        if (__any(tmax > m2 + DEFER_THR)) {                                     \
            float nm = fmaxf(m2, tmax);                                         \
            float sc = EXP2F(m2 - nm);                                          \
            _Pragma("unroll")                                                   \
            for (int r = 0; r < 16; ++r) acc[r] *= sc;                          \
            m2 = nm;                                                            \
        }                                                                       \
        unsigned phw[8], plw[8];                                                \
        _Pragma("unroll")                                                       \
        for (int jj = 0; jj < 8; ++jj) {                                        \
            float e0 = EXP2F(S[2 * jj] - m2);                                   \
            float e1 = EXP2F(S[2 * jj + 1] - m2);                               \
            phw[jj] = pack_tr(e0, e1);                                          \
            plw[jj] = pack_tr(e0 - trunc_bf(e0), e1 - trunc_bf(e1));            \
        }                                                                       \
        const s16x8 Bph0 = mk8(phw[0], phw[1], phw[2], phw[3]);                 \
        const s16x8 Bpl0 = mk8(plw[0], plw[1], plw[2], plw[3]);                 \
        const s16x8 Bph1 = mk8(phw[4], phw[5], phw[6], phw[7]);                 \
        const s16x8 Bpl1 = mk8(plw[4], plw[5], plw[6], plw[7]);                 \
        acc = __builtin_amdgcn_mfma_f32_32x32x16_bf16((F).vh0, Bph0, acc, 0, 0, 0); \
        acc = __builtin_amdgcn_mfma_f32_32x32x16_bf16((F).vl0, Bph0, acc, 0, 0, 0); \
        acc = __builtin_amdgcn_mfma_f32_32x32x16_bf16((F).vh0, Bpl0, acc, 0, 0, 0); \
        acc = __builtin_amdgcn_mfma_f32_32x32x16_bf16((F).vh1, Bph1, acc, 0, 0, 0); \
        acc = __builtin_amdgcn_mfma_f32_32x32x16_bf16((F).vl1, Bph1, acc, 0, 0, 0); \
        acc = __builtin_amdgcn_mfma_f32_32x32x16_bf16((F).vh1, Bpl1, acc, 0, 0, 0); \
    } while (0)

    // depth-1 register prefetch: loads for tile k issued one PROC ahead
    Frag f0, f1;
    LDF(f0, 0);
    for (int t = 0; t < ntile; t += 2) {
        LDF(f1, t + 1);
        PROC(f0);
        if (t + 2 < ntile) LDF(f0, t + 2);
        PROC(f1);
    }
#undef LDF
#undef PROC

    // --- block combine across the 4 candidate ranges ---
    if (hi == 0) lds_m[wave][s] = m2;
    __syncthreads();
    float mstar = fmaxf(fmaxf(lds_m[0][s], lds_m[1][s]), fmaxf(lds_m[2][s], lds_m[3][s]));
    float sw = EXP2F(m2 - mstar);
#pragma unroll
    for (int r = 0; r < 8; ++r) {                       // dv rows 0..15
        int dv = (r & 3) + 8 * (r >> 2) + 4 * hi;
        bufc[wave][dv][s] = acc[r] * sw;
    }
    if (hi == 0) {                                      // dv 16 = sum e*b, dv 17 = l
        bufc[wave][16][s] = acc[8] * sw;
        bufc[wave][17][s] = acc[9] * sw;
    }
    __syncthreads();

#pragma unroll
    for (int q = 0; q < 3; ++q) {
        int u = tid + 256 * q;
        if (u < 18 * 32) {
            int dv = u >> 5, ss = u & 31;
            bufc[0][dv][ss] = bufc[0][dv][ss] + bufc[1][dv][ss]
                            + bufc[2][dv][ss] + bufc[3][dv][ss];
        }
    }
    __syncthreads();

    {
        int ss = tid >> 3, d0 = (tid & 7) * 2;
        float inv = 1.0f / bufc[0][17][ss];
        float2 o = make_float2(bufc[0][d0][ss] * inv, bufc[0][d0 + 1][ss] * inv);
        *(float2*)(out + (size_t)(n0 + ss) * DD + d0) = o;
    }
    if (tid < 32) {
        float inv = 1.0f / bufc[0][17][tid];
        const float* xr = X + (size_t)(n0 + tid) * DD;
        float dot = 0.0f;
#pragma unroll
        for (int d = 0; d < DD; ++d) dot = fmaf(xr[d], bufc[0][d][tid], dot);
        out[(size_t)N * DD + n0 + tid] = (dot - bufc[0][16][tid]) * inv;
    }
}

extern "C" void kernel_launch(void* const* d_in, const int* in_sizes, int n_in,
                              void* d_out, int out_size, void* d_ws, size_t ws_size,
                              hipStream_t stream) {
    const float* X = (const float*)d_in[0];
    const float* Y = (const float*)d_in[1];
    const float* B = (const float*)d_in[2];
    float*     out = (float*)d_out;

    const int N = in_sizes[0] / DD;    // 32768
    const int C = in_sizes[2];         // 2048

    char* w = (char*)d_ws;
    unsigned short* YhA = (unsigned short*)(w);
    unsigned short* YlA = (unsigned short*)(w + (size_t)C * DD * 2);
    unsigned short* VhP = (unsigned short*)(w + (size_t)C * DD * 4);
    unsigned short* VlP = (unsigned short*)(w + (size_t)C * DD * 4 + (size_t)32 * C * 2);
    unsigned*       Bq  = (unsigned*)   (w + (size_t)C * DD * 4 + (size_t)32 * C * 4);

    hipLaunchKernelGGL(prep_kernel, dim3((C + 255) / 256), dim3(256), 0, stream,
                       Y, B, YhA, YlA, VhP, VlP, Bq, C);
    hipLaunchKernelGGL(finite_mfma, dim3(N / 32), dim3(256), 0, stream,
                       X, YhA, YlA, VhP, VlP, Bq, out, N, C);
}

// Round 8
// 86.737 us; speedup vs baseline: 2.1123x; 1.1036x over previous
//
#include <hip/hip_runtime.h>
#include <math.h>

#if defined(__has_builtin)
#  if __has_builtin(__builtin_amdgcn_exp2f)
#    define EXP2F(x) __builtin_amdgcn_exp2f(x)
#  else
#    define EXP2F(x) exp2f(x)
#  endif
#else
#  define EXP2F(x) exp2f(x)
#endif

constexpr int   DD = 16;
constexpr float T2 = 72.13475204444817f;   // 50/ln2
constexpr float DEFER_THR = 8.0f;          // T13 defer-max

typedef __attribute__((ext_vector_type(8)))  short s16x8;
typedef __attribute__((ext_vector_type(16))) float f32x16;

static __device__ __forceinline__ s16x8 mk8(unsigned a, unsigned b, unsigned c, unsigned d) {
    union { unsigned u[4]; s16x8 v; } x;
    x.u[0] = a; x.u[1] = b; x.u[2] = c; x.u[3] = d;
    return x.v;
}
static __device__ __forceinline__ unsigned pack_tr(float a, float b) {
    return (__float_as_uint(a) >> 16) | (__float_as_uint(b) & 0xFFFF0000u);
}
static __device__ __forceinline__ float trunc_bf(float a) {
    return __uint_as_float(__float_as_uint(a) & 0xFFFF0000u);
}
static __device__ __forceinline__ unsigned short rne16(float f) {
    unsigned u = __float_as_uint(f);
    return (unsigned short)((u + 0x7FFFu + ((u >> 16) & 1u)) >> 16);
}
static __device__ __forceinline__ float bfh2f(unsigned short h) {
    return __uint_as_float(((unsigned)h) << 16);
}

// ---------- prep (coalesced): Y -> bf16 hi/lo row-major (QK-A); V3 tiled [C/32][32 rows][32 slots]
// rows 0..15 = dims, 16 = b, 17 = 1.0, 18..31 = 0; slots crow-permuted within tile.
// Thread c: Y-row c (2x16B stores per buf) + V3-row (t=c>>5, r=c&31) (4x16B stores per buf). ----------
__global__ void prep_kernel(const float* __restrict__ Y, const float* __restrict__ B,
                            unsigned short* __restrict__ YhA, unsigned short* __restrict__ YlA,
                            unsigned short* __restrict__ V3h, unsigned short* __restrict__ V3l,
                            unsigned* __restrict__ Bq, int C)
{
    int c = blockIdx.x * blockDim.x + threadIdx.x;
    if (c >= C) return;

    // ---- Y split rows (contiguous per thread) ----
    union { unsigned short u[DD]; s16x8 v[2]; } hb, lb;
    const float* yr = Y + (size_t)c * DD;
#pragma unroll
    for (int d = 0; d < DD; ++d) {
        float y = yr[d];
        unsigned short h = rne16(y);
        hb.u[d] = h;
        lb.u[d] = rne16(y - bfh2f(h));
    }
    s16x8* yh = (s16x8*)(YhA + (size_t)c * DD);
    s16x8* yl = (s16x8*)(YlA + (size_t)c * DD);
    yh[0] = hb.v[0]; yh[1] = hb.v[1];
    yl[0] = lb.v[0]; yl[1] = lb.v[1];

    float bb = B[c];
    float qb = -T2 * bb;
    unsigned short qh = rne16(qb);
    Bq[c] = (unsigned)qh | ((unsigned)rne16(qb - bfh2f(qh)) << 16);

    // ---- V3 row (t, r): 32 slots, inverse-crow candidate per slot ----
    const int t = c >> 5, r = c & 31;
    union { unsigned short u[32]; s16x8 v[4]; } vh, vl;
#pragma unroll
    for (int slot = 0; slot < 32; ++slot) {
        int j = slot & 7, hs = (slot >> 3) & 1;
        int cl = (slot & 16) | (j & 3) | (hs << 2) | (((j >> 2) & 1) << 3);
        int cc = (t << 5) | cl;
        float v;
        if (r < DD)            v = Y[(size_t)cc * DD + r];
        else if (r == DD)      v = B[cc];       // row16 = b
        else if (r == DD + 1)  v = 1.0f;        // row17 = 1
        else                   v = 0.0f;
        unsigned short h = rne16(v);
        vh.u[slot] = h;
        vl.u[slot] = rne16(v - bfh2f(h));
    }
    s16x8* ph = (s16x8*)(V3h + ((size_t)t * 32 + r) * 32);
    s16x8* pl = (s16x8*)(V3l + ((size_t)t * 32 + r) * 32);
#pragma unroll
    for (int q = 0; q < 4; ++q) { ph[q] = vh.v[q]; pl[q] = vl.v[q]; }
}

struct Frag {
    s16x8 aYh, aYl, vh0, vh1, vl0, vl1;
    unsigned bw;
};

// ---------- main: flash softmax-matmul, 32 samples/block, 4 waves split C, reg double-buffer ----------
__global__ __launch_bounds__(256, 4)
void finite_mfma(const float* __restrict__ X,
                 const unsigned short* __restrict__ YhA, const unsigned short* __restrict__ YlA,
                 const unsigned short* __restrict__ V3h, const unsigned short* __restrict__ V3l,
                 const unsigned* __restrict__ Bq,
                 float* __restrict__ out, int N, int C)
{
    const int tid  = threadIdx.x;
    const int wave = tid >> 6, lane = tid & 63;
    const int s = lane & 31, hi = lane >> 5;
    const int n0 = blockIdx.x * 32;
    const int cpw = C >> 2, cbase = wave * cpw, ntile = cpw >> 5;   // 512 cands, 16 tiles

    __shared__ float bufc[4][18][32];
    __shared__ float lds_m[4][32];

    // streaming pointers; tile strides: Y 512 shorts, V3 1024 shorts, Bq 32 words
    const unsigned short* pYh = YhA + ((size_t)(cbase + s) * DD + 8 * hi);
    const unsigned short* pYl = YlA + ((size_t)(cbase + s) * DD + 8 * hi);
    const unsigned short* pVh = V3h + (((size_t)(cbase >> 5) * 32 + s) * 32 + 8 * hi);
    const unsigned short* pVl = V3l + (((size_t)(cbase >> 5) * 32 + s) * 32 + 8 * hi);
    const unsigned*       pBq = Bq + cbase + s;

    // X row for sample n0+s, this half's 8 dims, T2-scaled, trunc-split to bf16 hi/lo
    const float* xp = X + ((size_t)(n0 + s) * DD + 8 * hi);
    float xq[8];
#pragma unroll
    for (int jj = 0; jj < 8; ++jj) xq[jj] = xp[jj] * T2;
    unsigned xhw[4], xlw[4];
#pragma unroll
    for (int jj = 0; jj < 4; ++jj) {
        float a = xq[2 * jj], b = xq[2 * jj + 1];
        xhw[jj] = pack_tr(a, b);
        xlw[jj] = pack_tr(a - trunc_bf(a), b - trunc_bf(b));
    }
    const s16x8 xqh = mk8(xhw[0], xhw[1], xhw[2], xhw[3]);
    const s16x8 xql = mk8(xlw[0], xlw[1], xlw[2], xlw[3]);
    const s16x8 ones2 = mk8(hi ? 0u : 0x3F803F80u, 0u, 0u, 0u);

    f32x16 acc;
#pragma unroll
    for (int r = 0; r < 16; ++r) acc[r] = 0.0f;
    float m2 = -INFINITY;

#define LDF(F, k) do {                                              \
        (F).aYh = *(const s16x8*)(pYh + (size_t)(k) * 512);         \
        (F).aYl = *(const s16x8*)(pYl + (size_t)(k) * 512);         \
        (F).vh0 = *(const s16x8*)(pVh + (size_t)(k) * 1024);        \
        (F).vh1 = *(const s16x8*)(pVh + (size_t)(k) * 1024 + 16);   \
        (F).vl0 = *(const s16x8*)(pVl + (size_t)(k) * 1024);        \
        (F).vl1 = *(const s16x8*)(pVl + (size_t)(k) * 1024 + 16);   \
        (F).bw  = pBq[(size_t)(k) * 32];                            \
    } while (0)

#define PROC(F) do {                                                            \
        const s16x8 a2 = mk8(hi ? 0u : (F).bw, 0u, 0u, 0u);                     \
        f32x16 S;                                                               \
        _Pragma("unroll")                                                       \
        for (int r = 0; r < 16; ++r) S[r] = 0.0f;                               \
        S = __builtin_amdgcn_mfma_f32_32x32x16_bf16(a2,     ones2, S, 0, 0, 0); \
        S = __builtin_amdgcn_mfma_f32_32x32x16_bf16((F).aYh, xqh,  S, 0, 0, 0); \
        S = __builtin_amdgcn_mfma_f32_32x32x16_bf16((F).aYh, xql,  S, 0, 0, 0); \
        S = __builtin_amdgcn_mfma_f32_32x32x16_bf16((F).aYl, xqh,  S, 0, 0, 0); \
        float tm[8];                                                            \
        _Pragma("unroll")                                                       \
        for (int jj = 0; jj < 8; ++jj) tm[jj] = fmaxf(S[2 * jj], S[2 * jj + 1]);\
        _Pragma("unroll")                                                       \
        for (int jj = 0; jj < 4; ++jj) tm[jj] = fmaxf(tm[jj], tm[jj + 4]);      \
        tm[0] = fmaxf(fmaxf(tm[0], tm[2]), fmaxf(tm[1], tm[3]));                \
        float tmax = fmaxf(tm[0], __shfl_xor(tm[0], 32, 64));                   \
        if (__any(tmax > m2 + DEFER_THR)) {                                     \
            float nm = fmaxf(m2, tmax);                                         \
            float sc = EXP2F(m2 - nm);                                          \
            _Pragma("unroll")                                                   \
            for (int r = 0; r < 16; ++r) acc[r] *= sc;                          \
            m2 = nm;                                                            \
        }                                                                       \
        unsigned phw[8];                                                        \
        _Pragma("unroll")                                                       \
        for (int jj = 0; jj < 8; ++jj) {                                        \
            float e0 = EXP2F(S[2 * jj] - m2);                                   \
            float e1 = EXP2F(S[2 * jj + 1] - m2);                               \
            phw[jj] = pack_tr(e0, e1);                                          \
        }                                                                       \
        const s16x8 Bph0 = mk8(phw[0], phw[1], phw[2], phw[3]);                 \
        const s16x8 Bph1 = mk8(phw[4], phw[5], phw[6], phw[7]);                 \
        acc = __builtin_amdgcn_mfma_f32_32x32x16_bf16((F).vh0, Bph0, acc, 0, 0, 0); \
        acc = __builtin_amdgcn_mfma_f32_32x32x16_bf16((F).vl0, Bph0, acc, 0, 0, 0); \
        acc = __builtin_amdgcn_mfma_f32_32x32x16_bf16((F).vh1, Bph1, acc, 0, 0, 0); \
        acc = __builtin_amdgcn_mfma_f32_32x32x16_bf16((F).vl1, Bph1, acc, 0, 0, 0); \
    } while (0)

    // depth-1 register prefetch
    Frag f0, f1;
    LDF(f0, 0);
    for (int t = 0; t < ntile; t += 2) {
        LDF(f1, t + 1);
        PROC(f0);
        if (t + 2 < ntile) LDF(f0, t + 2);
        PROC(f1);
    }
#undef LDF
#undef PROC

    // --- block combine across the 4 candidate ranges ---
    if (hi == 0) lds_m[wave][s] = m2;
    __syncthreads();
    float mstar = fmaxf(fmaxf(lds_m[0][s], lds_m[1][s]), fmaxf(lds_m[2][s], lds_m[3][s]));
    float sw = EXP2F(m2 - mstar);
#pragma unroll
    for (int r = 0; r < 8; ++r) {                       // dv rows 0..15
        int dv = (r & 3) + 8 * (r >> 2) + 4 * hi;
        bufc[wave][dv][s] = acc[r] * sw;
    }
    if (hi == 0) {                                      // dv16 = sum e*b (acc[8]), dv17 = l (acc[9])
        bufc[wave][16][s] = acc[8] * sw;
        bufc[wave][17][s] = acc[9] * sw;
    }
    __syncthreads();

#pragma unroll
    for (int q = 0; q < 3; ++q) {
        int u = tid + 256 * q;
        if (u < 18 * 32) {
            int dv = u >> 5, ss = u & 31;
            bufc[0][dv][ss] = bufc[0][dv][ss] + bufc[1][dv][ss]
                            + bufc[2][dv][ss] + bufc[3][dv][ss];
        }
    }
    __syncthreads();

    {
        int ss = tid >> 3, d0 = (tid & 7) * 2;
        float inv = 1.0f / bufc[0][17][ss];
        float2 o = make_float2(bufc[0][d0][ss] * inv, bufc[0][d0 + 1][ss] * inv);
        *(float2*)(out + (size_t)(n0 + ss) * DD + d0) = o;
    }
    if (tid < 32) {
        float inv = 1.0f / bufc[0][17][tid];
        const float* xr = X + (size_t)(n0 + tid) * DD;
        float dot = 0.0f;
#pragma unroll
        for (int d = 0; d < DD; ++d) dot = fmaf(xr[d], bufc[0][d][tid], dot);
        out[(size_t)N * DD + n0 + tid] = (dot - bufc[0][16][tid]) * inv;
    }
}

extern "C" void kernel_launch(void* const* d_in, const int* in_sizes, int n_in,
                              void* d_out, int out_size, void* d_ws, size_t ws_size,
                              hipStream_t stream) {
    const float* X = (const float*)d_in[0];
    const float* Y = (const float*)d_in[1];
    const float* B = (const float*)d_in[2];
    float*     out = (float*)d_out;

    const int N = in_sizes[0] / DD;    // 32768
    const int C = in_sizes[2];         // 2048

    char* w = (char*)d_ws;
    unsigned short* YhA = (unsigned short*)(w);
    unsigned short* YlA = (unsigned short*)(w + (size_t)C * DD * 2);
    unsigned short* V3h = (unsigned short*)(w + (size_t)C * DD * 4);
    unsigned short* V3l = (unsigned short*)(w + (size_t)C * DD * 4 + (size_t)32 * C * 2);
    unsigned*       Bq  = (unsigned*)   (w + (size_t)C * DD * 4 + (size_t)32 * C * 4);

    hipLaunchKernelGGL(prep_kernel, dim3((C + 255) / 256), dim3(256), 0, stream,
                       Y, B, YhA, YlA, V3h, V3l, Bq, C);
    hipLaunchKernelGGL(finite_mfma, dim3(N / 32), dim3(256), 0, stream,
                       X, YhA, YlA, V3h, V3l, Bq, out, N, C);
}